// Round 3
// baseline (96.622 us; speedup 1.0000x reference)
//
#include <hip/hip_runtime.h>

#define N_PTS   4096
#define N_BATCH 16
#define INV_CNT (1.0f / (2.0f * N_BATCH * N_PTS))

typedef _Float16 f16x8  __attribute__((ext_vector_type(8)));
#define AS3 __attribute__((address_space(3)))

// R17: byte-identical compute to R2's fused kernel, plus ONE redundant
// chamfer launch targeting scratch (d_ws) -- pure measurement round.
// dur_new - dur_R2 == chamfer dispatch duration + one launch gap.
// (out is untouched by the duplicate -> absmax unchanged.)

__device__ inline void pack_pt(float x, float y, float z, AS3 _Float16* lp) {
    float o2 = fmaf(x, x, fmaf(y, y, z * z));
    _Float16 xh = (_Float16)x, yh = (_Float16)y, zh = (_Float16)z;
    _Float16 xl = (_Float16)(x - (float)xh);
    _Float16 yl = (_Float16)(y - (float)yh);
    _Float16 zl = (_Float16)(z - (float)zh);
    _Float16 o2h = (_Float16)o2;
    _Float16 o2l = (_Float16)(o2 - (float)o2h);
    const _Float16 m2 = (_Float16)-2.0f;              // exact power-of-2 scale
    f16x8 v0, v1;
    v0[0] = m2 * xh; v0[1] = m2 * yh; v0[2] = m2 * zh;
    v0[3] = m2 * xl; v0[4] = m2 * yl; v0[5] = m2 * zl;
    v0[6] = m2 * xh; v0[7] = m2 * yh;
    v1[0] = m2 * zh; v1[1] = o2h; v1[2] = o2l;
    v1[3] = (_Float16)0.0f; v1[4] = (_Float16)0.0f; v1[5] = (_Float16)0.0f;
    v1[6] = (_Float16)0.0f; v1[7] = (_Float16)0.0f;
    *(AS3 f16x8*)lp       = v0;
    *(AS3 f16x8*)(lp + 8) = v1;
}

#define FD(a,x,y) "v_min3_f32 %[" #a "], v" #x ", v" #y ", %[" #a "]\n\t"
#define FOLD_A FD(acc0,32,33) FD(acc1,34,35) FD(acc0,36,37) FD(acc1,38,39) \
               FD(acc0,40,41) FD(acc1,42,43) FD(acc0,44,45) FD(acc1,46,47) \
               FD(acc2,64,65) FD(acc3,66,67) FD(acc2,68,69) FD(acc3,70,71) \
               FD(acc2,72,73) FD(acc3,74,75) FD(acc2,76,77) FD(acc3,78,79)
#define FOLD_B FD(acc0,48,49) FD(acc1,50,51) FD(acc0,52,53) FD(acc1,54,55) \
               FD(acc0,56,57) FD(acc1,58,59) FD(acc0,60,61) FD(acc1,62,63) \
               FD(acc2,80,81) FD(acc3,82,83) FD(acc2,84,85) FD(acc3,86,87) \
               FD(acc2,88,89) FD(acc3,90,91) FD(acc2,92,93) FD(acc3,94,95)
#define MF_A(d) \
  "v_mfma_f32_32x32x16_f16 v[32:47], %[" #d "], %[bf0], v[96:111]\n\t" \
  "v_mfma_f32_32x32x16_f16 v[64:79], %[" #d "], %[bf1], v[96:111]\n\t"
#define MF_B(d) \
  "v_mfma_f32_32x32x16_f16 v[48:63], %[" #d "], %[bf0], v[96:111]\n\t" \
  "v_mfma_f32_32x32x16_f16 v[80:95], %[" #d "], %[bf1], v[96:111]\n\t"
#define DSR(d,off) "ds_read_b128 %[" #d "], %[dsa] offset:" #off "\n\t"
#define WL(n) "s_waitcnt lgkmcnt(" #n ")\n\t"
#define ZM(r) "v_mov_b32 v" #r ", 0\n\t"
#define NOP3 "s_nop 7\n\t" "s_nop 7\n\t" "s_nop 7\n\t"

// Grid (16,16,2) = 512 blocks x 4 waves, 2 blocks/CU.
__global__ __launch_bounds__(256, 2) void chamfer_fused(
    const float* __restrict__ tpl, const float* __restrict__ src,
    float* __restrict__ out) {
    __shared__ uint4 sbuf[2][1024];   // 2 x 16 KB packed-A chunk buffers
    __shared__ float wsum[4];

    const int tid = threadIdx.x;
    const int wv = tid >> 6, lane = tid & 63;
    const int n = lane & 31, g = lane >> 5;           // B col / K-half group
    // --- XCD-locality remap (bijection on [0,512)) ---
    const int lin = blockIdx.x + 16 * (blockIdx.y + 16 * blockIdx.z);
    const int s_  = lin >> 3;
    const int qb  = s_ & 15;
    const int region = (lin & 7) + 8 * (s_ >> 4);     // region -> 1 XCD
    const int batch  = region & 15;
    const int dir    = region >> 4;

    const float* qpts = (dir == 0) ? src : tpl;       // dist1: query = source
    const float* araw = ((dir == 0) ? tpl : src)      // raw opposite-set slice
                      + (size_t)batch * 4096 * 3;

    // Two B fragments (frag i -> query qb*256 + wv*64 + i*32 + n) + |p|^2.
    f16x8 bfr[2];
    float p2[2];
    #pragma unroll
    for (int i = 0; i < 2; ++i) {
        const int q = qb * 256 + wv * 64 + i * 32 + n;
        const float* p = qpts + (size_t)(batch * 4096 + q) * 3;
        float px = p[0], py = p[1], pz = p[2];
        p2[i] = fmaf(px, px, fmaf(py, py, pz * pz));
        _Float16 xh = (_Float16)px, yh = (_Float16)py, zh = (_Float16)pz;
        _Float16 xl = (_Float16)(px - (float)xh);
        _Float16 yl = (_Float16)(py - (float)yh);
        _Float16 zl = (_Float16)(pz - (float)zh);
        f16x8 b;
        if (g == 0) {
            b[0] = xh; b[1] = yh; b[2] = zh;
            b[3] = xh; b[4] = yh; b[5] = zh;
            b[6] = xl; b[7] = yl;
        } else {
            b[0] = zl; b[1] = (_Float16)1.0f; b[2] = (_Float16)1.0f;
            b[3] = (_Float16)0.0f; b[4] = (_Float16)0.0f; b[5] = (_Float16)0.0f;
            b[6] = (_Float16)0.0f; b[7] = (_Float16)0.0f;
        }
        bfr[i] = b;
    }

    const int lane_off = n * 32 + g * 16;
    const unsigned dsa0 = (unsigned)(size_t)((AS3 char*)&sbuf[0][0]) + lane_off;
    const unsigned dsa1 = (unsigned)(size_t)((AS3 char*)&sbuf[1][0]) + lane_off;

    float r0, r1, r2, r3, r4, r5;
    #define ALOAD(ch)                                                          \
        {                                                                      \
            const float* gp = araw + (size_t)(ch) * 1536 + tid * 3;            \
            r0 = gp[0]; r1 = gp[1]; r2 = gp[2];                                \
            r3 = gp[768]; r4 = gp[769]; r5 = gp[770];                          \
        }
    #define APACK(ch)                                                          \
        {                                                                      \
            AS3 _Float16* lp = (AS3 _Float16*)&sbuf[(ch) & 1][0];              \
            pack_pt(r0, r1, r2, lp + tid * 16);                                \
            pack_pt(r3, r4, r5, lp + (tid + 256) * 16);                        \
        }

    float acc0 = 1e30f, acc1 = 1e30f, acc2 = 1e30f, acc3 = 1e30f;
    f16x8 d0, d1, d2, d3;

    ALOAD(0)
    APACK(0)
    ALOAD(1)                               // prefetch chunk 1
    __syncthreads();                       // chunk 0 visible to all waves

    #pragma unroll 1
    for (int c = 0; c < 8; ++c) {
        if (c < 7) {
            APACK(c + 1)                   // write next buf (parity ~c) ...
            if (c < 6) ALOAD(c + 2)        // ... and prefetch the one after
        }
        const unsigned dsa = (c & 1) ? dsa1 : dsa0;

        asm volatile(
            ZM(96) ZM(97) ZM(98) ZM(99) ZM(100) ZM(101) ZM(102) ZM(103)
            ZM(104) ZM(105) ZM(106) ZM(107) ZM(108) ZM(109) ZM(110) ZM(111)
            DSR(d0,0) DSR(d1,1024) DSR(d2,2048) DSR(d3,3072)
            WL(3) MF_A(d0) DSR(d0,4096) NOP3
            WL(3) MF_B(d1) DSR(d1,5120)  FOLD_A      // t1
            WL(3) MF_A(d2) DSR(d2,6144)  FOLD_B      // t2
            WL(3) MF_B(d3) DSR(d3,7168)  FOLD_A      // t3
            WL(3) MF_A(d0) DSR(d0,8192)  FOLD_B      // t4
            WL(3) MF_B(d1) DSR(d1,9216)  FOLD_A      // t5
            WL(3) MF_A(d2) DSR(d2,10240) FOLD_B      // t6
            WL(3) MF_B(d3) DSR(d3,11264) FOLD_A      // t7
            WL(3) MF_A(d0) DSR(d0,12288) FOLD_B      // t8
            WL(3) MF_B(d1) DSR(d1,13312) FOLD_A      // t9
            WL(3) MF_A(d2) DSR(d2,14336) FOLD_B      // t10
            WL(3) MF_B(d3) DSR(d3,15360) FOLD_A      // t11
            WL(3) MF_A(d0) FOLD_B                    // t12
            WL(2) MF_B(d1) FOLD_A                    // t13
            WL(1) MF_A(d2) FOLD_B                    // t14
            WL(0) MF_B(d3) FOLD_A                    // t15
            NOP3 FOLD_B                              // tail: t15's D
            : [d0]"=&v"(d0), [d1]"=&v"(d1), [d2]"=&v"(d2), [d3]"=&v"(d3),
              [acc0]"+v"(acc0), [acc1]"+v"(acc1),
              [acc2]"+v"(acc2), [acc3]"+v"(acc3)
            : [bf0]"v"(bfr[0]), [bf1]"v"(bfr[1]), [dsa]"v"(dsa)
            : "memory",
              "v32","v33","v34","v35","v36","v37","v38","v39",
              "v40","v41","v42","v43","v44","v45","v46","v47",
              "v48","v49","v50","v51","v52","v53","v54","v55",
              "v56","v57","v58","v59","v60","v61","v62","v63",
              "v64","v65","v66","v67","v68","v69","v70","v71",
              "v72","v73","v74","v75","v76","v77","v78","v79",
              "v80","v81","v82","v83","v84","v85","v86","v87",
              "v88","v89","v90","v91","v92","v93","v94","v95",
              "v96","v97","v98","v99","v100","v101","v102","v103",
              "v104","v105","v106","v107","v108","v109","v110","v111");

        if (c < 7) __syncthreads();
    }

    // Per-frag: rows split across lane halves; fold, clamp, sqrt.
    float v0 = fminf(acc0, acc1);
    v0 = fminf(v0, __shfl_xor(v0, 32));
    float v1 = fminf(acc2, acc3);
    v1 = fminf(v1, __shfl_xor(v1, 32));
    float dd0 = fmaxf(v0 + p2[0], 0.0f);               // == min of clamped
    float dd1 = fmaxf(v1 + p2[1], 0.0f);
    float s = (sqrtf(dd0) + sqrtf(dd1)) * INV_CNT;
    if (g != 0) s = 0.0f;                              // count each query once
    #pragma unroll
    for (int off = 32; off > 0; off >>= 1) s += __shfl_down(s, off);
    if (lane == 0) wsum[wv] = s;
    __syncthreads();
    if (tid == 0)
        atomicAdd(out, wsum[0] + wsum[1] + wsum[2] + wsum[3]);
}

extern "C" void kernel_launch(void* const* d_in, const int* in_sizes, int n_in,
                              void* d_out, int out_size, void* d_ws, size_t ws_size,
                              hipStream_t stream) {
    const float* tpl = (const float*)d_in[0];
    const float* src = (const float*)d_in[1];
    float* out = (float*)d_out;
    (void)in_sizes; (void)n_in; (void)out_size;

    hipMemsetAsync(out, 0, sizeof(float), stream);     // 4 B, graph-capturable
    dim3 grid(N_PTS / 256, N_BATCH, 2);                // (16, 16, 2) = 512 blocks
    hipLaunchKernelGGL(chamfer_fused, grid, dim3(256), 0, stream,
                       tpl, src, out);
    // --- measurement duplicate: identical work, scratch accumulator in d_ws.
    // dur_us(R17) - dur_us(R16) == chamfer dispatch time + 1 launch gap.
    if (ws_size >= sizeof(float)) {
        float* dummy = (float*)d_ws;                   // poisoned scratch; never read
        hipLaunchKernelGGL(chamfer_fused, grid, dim3(256), 0, stream,
                           tpl, src, dummy);
    }
}

// Round 4
// 77.675 us; speedup vs baseline: 1.2439x; 1.2439x over previous
//
#include <hip/hip_runtime.h>

#define N_PTS   4096
#define N_BATCH 16
#define INV_CNT (1.0f / (2.0f * N_BATCH * N_PTS))
#define AROW_BYTES ((size_t)2 * N_BATCH * N_PTS * 16 * 2)   // 4 MB
#define NQUERY (2 * N_BATCH * N_PTS)                        // 131072
#define NFBLK  128                 // final-kernel blocks

typedef _Float16 f16x8  __attribute__((ext_vector_type(8)));
#define AS1 __attribute__((address_space(1)))
#define AS3 __attribute__((address_space(3)))

// 32x32x16 f16 MFMA, K-slot packing (split o = oh + ol, p = ph + pl in f16):
//   A-row (opposite point o): [-2oh_x,-2oh_y,-2oh_z, -2ol_x,-2ol_y,-2ol_z,
//                              -2oh_x,-2oh_y | -2oh_z, o2h, o2l, 0...]
//   B-col (query p):          [ph_x,ph_y,ph_z, ph_x,ph_y,ph_z, pl_x,pl_y |
//                              pl_z, 1, 1, 0...]
//   => C = |o|^2 - 2 o.p   (dropped ol.pl ~2^-22; verified R5-R14, absmax 0.0)
//
// R18: back to the R0 three-kernel structure (R3's instrumented round showed
// launch gaps ~0.5us and R0-chamfer ~12.8us vs fused 19us). New lever:
// A-SPLIT x2 -- 1024 blocks x 4 chunks (was 512 x 8). Per-wave structure and
// totals are identical; occupancy goes 2 -> 3-4 blocks/CU (launch_bounds
// (256,3)) to hide the ds_read/MFMA/fold latency chain that keeps chamfer 3x
// above its VALU floor. Halves are combined via a 1 MB qmin slab (plain
// stores, clamped mins -> min-of-clamped == clamp-of-min) + final kernel.
__global__ __launch_bounds__(256) void prep_kernel(
    const float* __restrict__ tpl, const float* __restrict__ src,
    _Float16* __restrict__ arow, float* __restrict__ out) {
    int pt = blockIdx.x * 256 + threadIdx.x;          // 0..131071 (T set, then S set)
    if (pt == 0) out[0] = 0.0f;                       // final_kernel accumulates
    const float* p = (pt < 65536 ? tpl : src) + (size_t)(pt & 65535) * 3;
    float x = p[0], y = p[1], z = p[2];
    float o2 = fmaf(x, x, fmaf(y, y, z * z));
    _Float16 xh = (_Float16)x, yh = (_Float16)y, zh = (_Float16)z;
    _Float16 xl = (_Float16)(x - (float)xh);
    _Float16 yl = (_Float16)(y - (float)yh);
    _Float16 zl = (_Float16)(z - (float)zh);
    _Float16 o2h = (_Float16)o2;
    _Float16 o2l = (_Float16)(o2 - (float)o2h);
    const _Float16 m2 = (_Float16)-2.0f;              // exact power-of-2 scale
    f16x8 v0, v1;
    v0[0] = m2 * xh; v0[1] = m2 * yh; v0[2] = m2 * zh;
    v0[3] = m2 * xl; v0[4] = m2 * yl; v0[5] = m2 * zl;
    v0[6] = m2 * xh; v0[7] = m2 * yh;
    v1[0] = m2 * zh; v1[1] = o2h; v1[2] = o2l;
    v1[3] = (_Float16)0.0f; v1[4] = (_Float16)0.0f; v1[5] = (_Float16)0.0f;
    v1[6] = (_Float16)0.0f; v1[7] = (_Float16)0.0f;
    *(f16x8*)(arow + (size_t)pt * 16)     = v0;
    *(f16x8*)(arow + (size_t)pt * 16 + 8) = v1;
}

// ---- asm blocks (chunk-local register state only). Banks: A = v[32:47]
// (frag0) + v[64:79] (frag1); B = v[48:63] + v[80:95]; zero-C = v[96:111],
// re-zeroed per chunk. Proven R0 schedule, verbatim. ----
#define FD(a,x,y) "v_min3_f32 %[" #a "], v" #x ", v" #y ", %[" #a "]\n\t"
#define FOLD_A FD(acc0,32,33) FD(acc1,34,35) FD(acc0,36,37) FD(acc1,38,39) \
               FD(acc0,40,41) FD(acc1,42,43) FD(acc0,44,45) FD(acc1,46,47) \
               FD(acc2,64,65) FD(acc3,66,67) FD(acc2,68,69) FD(acc3,70,71) \
               FD(acc2,72,73) FD(acc3,74,75) FD(acc2,76,77) FD(acc3,78,79)
#define FOLD_B FD(acc0,48,49) FD(acc1,50,51) FD(acc0,52,53) FD(acc1,54,55) \
               FD(acc0,56,57) FD(acc1,58,59) FD(acc0,60,61) FD(acc1,62,63) \
               FD(acc2,80,81) FD(acc3,82,83) FD(acc2,84,85) FD(acc3,86,87) \
               FD(acc2,88,89) FD(acc3,90,91) FD(acc2,92,93) FD(acc3,94,95)
#define MF_A(d) \
  "v_mfma_f32_32x32x16_f16 v[32:47], %[" #d "], %[bf0], v[96:111]\n\t" \
  "v_mfma_f32_32x32x16_f16 v[64:79], %[" #d "], %[bf1], v[96:111]\n\t"
#define MF_B(d) \
  "v_mfma_f32_32x32x16_f16 v[48:63], %[" #d "], %[bf0], v[96:111]\n\t" \
  "v_mfma_f32_32x32x16_f16 v[80:95], %[" #d "], %[bf1], v[96:111]\n\t"
#define DSR(d,off) "ds_read_b128 %[" #d "], %[dsa] offset:" #off "\n\t"
#define WL(n) "s_waitcnt lgkmcnt(" #n ")\n\t"
#define ZM(r) "v_mov_b32 v" #r ", 0\n\t"
#define NOP3 "s_nop 7\n\t" "s_nop 7\n\t" "s_nop 7\n\t"

// Grid (16,16,4) = 1024 blocks x 4 waves; target 3-4 blocks/CU.
__global__ __launch_bounds__(256, 3) void chamfer_mfma(
    const float* __restrict__ tpl, const float* __restrict__ src,
    const _Float16* __restrict__ arow, float* __restrict__ qmin) {
    __shared__ uint4 sbuf[2][1024];   // 2 x 16 KB chunk buffers

    const int tid = threadIdx.x;
    const int wv = tid >> 6, lane = tid & 63;
    const int n = lane & 31, g = lane >> 5;           // B col / K-half group
    // --- XCD-locality remap (bijection on [0,1024)): 128-run per XCD,
    // consecutive runs share (dir,ahalf,batch) A-slices in that XCD's L2 ---
    const int lin = blockIdx.x + 16 * (blockIdx.y + 16 * blockIdx.z);
    const int wgid  = (lin & 7) * 128 + (lin >> 3);
    const int qb    = wgid & 15;
    const int batch = (wgid >> 4) & 15;
    const int dh    = wgid >> 8;                      // 0..3
    const int dir   = dh >> 1;
    const int ahalf = dh & 1;                         // which 2048-pt A half

    const float* qpts = (dir == 0) ? src : tpl;       // dist1: query = source
    const _Float16* abase = arow + ((dir == 0) ? (size_t)0 : (size_t)65536 * 16)
                          + (size_t)batch * 4096 * 16
                          + (size_t)ahalf * 2048 * 16;

    // Two B fragments (frag i -> query qb*256 + wv*64 + i*32 + n) + |p|^2.
    f16x8 bfr[2];
    float p2[2];
    #pragma unroll
    for (int i = 0; i < 2; ++i) {
        const int q = qb * 256 + wv * 64 + i * 32 + n;
        const float* p = qpts + (size_t)(batch * 4096 + q) * 3;
        float px = p[0], py = p[1], pz = p[2];
        p2[i] = fmaf(px, px, fmaf(py, py, pz * pz));
        _Float16 xh = (_Float16)px, yh = (_Float16)py, zh = (_Float16)pz;
        _Float16 xl = (_Float16)(px - (float)xh);
        _Float16 yl = (_Float16)(py - (float)yh);
        _Float16 zl = (_Float16)(pz - (float)zh);
        f16x8 b;
        if (g == 0) {
            b[0] = xh; b[1] = yh; b[2] = zh;
            b[3] = xh; b[4] = yh; b[5] = zh;
            b[6] = xl; b[7] = yl;
        } else {
            b[0] = zl; b[1] = (_Float16)1.0f; b[2] = (_Float16)1.0f;
            b[3] = (_Float16)0.0f; b[4] = (_Float16)0.0f; b[5] = (_Float16)0.0f;
            b[6] = (_Float16)0.0f; b[7] = (_Float16)0.0f;
        }
        bfr[i] = b;
    }

    const int lane_off = n * 32 + g * 16;
    const unsigned dsa0 = (unsigned)(size_t)((AS3 char*)&sbuf[0][0]) + lane_off;

    // Wave's staging share: 4 KB of each 16 KB chunk, 4 x 1 KB load_lds.
    const char* gwave = (const char*)abase + wv * 4096 + lane * 16;
    #define STAGE(ch)                                                          \
        {                                                                      \
            const char* gp = gwave + (size_t)(ch) * 16384;                     \
            AS3 char* lp = (AS3 char*)&sbuf[(ch) & 1][0] + wv * 4096;          \
            _Pragma("unroll")                                                  \
            for (int j = 0; j < 4; ++j)                                        \
                __builtin_amdgcn_global_load_lds(                              \
                    (const AS1 unsigned*)(gp + j * 1024),                      \
                    (AS3 unsigned*)(lp + j * 1024), 16, 0, 0);                 \
        }

    float acc0 = 1e30f, acc1 = 1e30f, acc2 = 1e30f, acc3 = 1e30f;
    f16x8 d0, d1, d2, d3;

    STAGE(0)
    #pragma unroll 1
    for (int c = 0; c < 4; ++c) {
        if (c < 3) STAGE(c + 1)
        if (c < 3)
            asm volatile("s_waitcnt vmcnt(4)\n\ts_barrier" ::: "memory");
        else
            asm volatile("s_waitcnt vmcnt(0)\n\ts_barrier" ::: "memory");
        const unsigned dsa = dsa0 + ((unsigned)(c & 1) << 14);  // +16384 for buf 1

        asm volatile(
            ZM(96) ZM(97) ZM(98) ZM(99) ZM(100) ZM(101) ZM(102) ZM(103)
            ZM(104) ZM(105) ZM(106) ZM(107) ZM(108) ZM(109) ZM(110) ZM(111)
            DSR(d0,0) DSR(d1,1024) DSR(d2,2048) DSR(d3,3072)
            // t0 (A banks, no fold; NOP3 protects t1's fold of t0's D)
            WL(3) MF_A(d0) DSR(d0,4096) NOP3
            WL(3) MF_B(d1) DSR(d1,5120)  FOLD_A      // t1
            WL(3) MF_A(d2) DSR(d2,6144)  FOLD_B      // t2
            WL(3) MF_B(d3) DSR(d3,7168)  FOLD_A      // t3
            WL(3) MF_A(d0) DSR(d0,8192)  FOLD_B      // t4
            WL(3) MF_B(d1) DSR(d1,9216)  FOLD_A      // t5
            WL(3) MF_A(d2) DSR(d2,10240) FOLD_B      // t6
            WL(3) MF_B(d3) DSR(d3,11264) FOLD_A      // t7
            WL(3) MF_A(d0) DSR(d0,12288) FOLD_B      // t8
            WL(3) MF_B(d1) DSR(d1,13312) FOLD_A      // t9
            WL(3) MF_A(d2) DSR(d2,14336) FOLD_B      // t10
            WL(3) MF_B(d3) DSR(d3,15360) FOLD_A      // t11
            WL(3) MF_A(d0) FOLD_B                    // t12
            WL(2) MF_B(d1) FOLD_A                    // t13
            WL(1) MF_A(d2) FOLD_B                    // t14
            WL(0) MF_B(d3) FOLD_A                    // t15
            NOP3 FOLD_B                              // tail: t15's D
            : [d0]"=&v"(d0), [d1]"=&v"(d1), [d2]"=&v"(d2), [d3]"=&v"(d3),
              [acc0]"+v"(acc0), [acc1]"+v"(acc1),
              [acc2]"+v"(acc2), [acc3]"+v"(acc3)
            : [bf0]"v"(bfr[0]), [bf1]"v"(bfr[1]), [dsa]"v"(dsa)
            : "memory",
              "v32","v33","v34","v35","v36","v37","v38","v39",
              "v40","v41","v42","v43","v44","v45","v46","v47",
              "v48","v49","v50","v51","v52","v53","v54","v55",
              "v56","v57","v58","v59","v60","v61","v62","v63",
              "v64","v65","v66","v67","v68","v69","v70","v71",
              "v72","v73","v74","v75","v76","v77","v78","v79",
              "v80","v81","v82","v83","v84","v85","v86","v87",
              "v88","v89","v90","v91","v92","v93","v94","v95",
              "v96","v97","v98","v99","v100","v101","v102","v103",
              "v104","v105","v106","v107","v108","v109","v110","v111");

        // all this wave's ds_reads retired (t15 waited lgkmcnt(0)):
        asm volatile("s_barrier" ::: "memory");  // buffer safe to re-stage
    }

    // Per-frag: rows split across lane halves; fold, clamp, store this
    // half's per-query min (clamped -> min across halves == clamp of min).
    float v0 = fminf(acc0, acc1);
    v0 = fminf(v0, __shfl_xor(v0, 32));
    float v1 = fminf(acc2, acc3);
    v1 = fminf(v1, __shfl_xor(v1, 32));
    float dd0 = fmaxf(v0 + p2[0], 0.0f);
    float dd1 = fmaxf(v1 + p2[1], 0.0f);
    if (g == 0) {
        const int qid = ((dir * N_BATCH + batch) << 12) + qb * 256 + wv * 64 + n;
        qmin[(size_t)ahalf * NQUERY + qid]      = dd0;   // frag0 (cols +0)
        qmin[(size_t)ahalf * NQUERY + qid + 32] = dd1;   // frag1 (cols +32)
    }
}

// Combine the two A-halves, sqrt, reduce 131072 queries -> out[0].
__global__ __launch_bounds__(256) void final_kernel(
    const float* __restrict__ qmin, float* __restrict__ out) {
    __shared__ float wsum[4];
    float s = 0.0f;
    const int base = blockIdx.x * (NQUERY / NFBLK) + threadIdx.x;
    #pragma unroll
    for (int j = 0; j < NQUERY / NFBLK / 256; ++j) {
        const int q = base + j * 256;
        s += sqrtf(fminf(qmin[q], qmin[NQUERY + q]));
    }
    s *= INV_CNT;
    #pragma unroll
    for (int off = 32; off > 0; off >>= 1) s += __shfl_down(s, off);
    if ((threadIdx.x & 63) == 0) wsum[threadIdx.x >> 6] = s;
    __syncthreads();
    if (threadIdx.x == 0)
        atomicAdd(out, wsum[0] + wsum[1] + wsum[2] + wsum[3]);
}

extern "C" void kernel_launch(void* const* d_in, const int* in_sizes, int n_in,
                              void* d_out, int out_size, void* d_ws, size_t ws_size,
                              hipStream_t stream) {
    const float* tpl = (const float*)d_in[0];
    const float* src = (const float*)d_in[1];
    float* out = (float*)d_out;
    _Float16* arow = (_Float16*)d_ws;                  // 4 MB
    float* qmin = (float*)((char*)d_ws + AROW_BYTES);  // 1 MB (2 x 131072 f32)
    (void)in_sizes; (void)n_in; (void)out_size; (void)ws_size;

    hipLaunchKernelGGL(prep_kernel, dim3((2 * N_BATCH * N_PTS) / 256),
                       dim3(256), 0, stream, tpl, src, arow, out);
    dim3 grid(N_PTS / 256, N_BATCH, 4);                // (16, 16, 4) = 1024 blocks
    hipLaunchKernelGGL(chamfer_mfma, grid, dim3(256), 0, stream,
                       tpl, src, arow, qmin);
    hipLaunchKernelGGL(final_kernel, dim3(NFBLK), dim3(256), 0, stream,
                       qmin, out);
}